// Round 10
// baseline (3782.828 us; speedup 1.0000x reference)
//
#include <hip/hip_runtime.h>
#include <hip/hip_bf16.h>

#define DT 0.1f
#define TAU_HP 12.3f
#define TAU_LP 2.3f
#define SCAN_B 1024
#define CHUNK 32768        // edges per block in hist/bin passes (64K regressed: R10)

// R12 tiling: tile = SR sources x RB targets. Balanced so edges/tile (~17K)
// >= staged floats (16K), and flush (n^2/SR) ~ staging (n^2/RB) ~ 10-20MB.
#define RB 8192
#define RBBITS 13
#define SR 16384
#define SRBITS 14
#define BKMAX 512          // >= ceil(n/RB)*ceil(n/SR) = 25*13 = 325

// ---------------------------------------------------------------------------
// R5:  8 lanes/row remap. NEUTRAL -> not wave-slot-bound.
// R6:  cooperative all-steps kernel. 9457us. REVERTED.
// R7:  relu-mask w/ global reads. 2179us: mask load was itself VMEM.
// R8:  mask in LDS. 1779us WIN (best). Step bound by random VMEM request
//      processing (~3cy/line-req -> 28us/step).
// R9:  direct-scatter build. 2123us (346MB writes). REVERTED.
// R10: CHUNK 64K. 1828us (bin occupancy halved). REVERTED.
// R11: tiled gather w/ RB=512: 3552us. Tile shape wrong: 1100 edges/bucket
//      = 1 edge/thread between barriers; staging reuse 0.07x. Tile ALGEBRA:
//      edges/tile = nnz*SR*RB/n^2; staging ~ n^2/RB; flush ~ n^2/SR.
// R12: balanced tiles SR=16K x RB=8K: 17.2K edges/tile (16.8/thread),
//      staging 20MB/step, flush 10.4MB/step coalesced atomics, 325 blocks,
//      LDS 96KB (1 blk/CU, 16 waves). gacc partial-sum + update kernel.
//      Side bonus: 325 buckets -> bin writes ~800B/bucket/block (was 168B)
//      -> write amp ~2x lower; scans 5x smaller.
// ---------------------------------------------------------------------------

__global__ void init_kernel(float* __restrict__ vA,
                            float* __restrict__ tm1_f,
                            float* __restrict__ gacc,
                            int n_neurons, int n_tm1) {
    int i = blockIdx.x * blockDim.x + threadIdx.x;
    if (i < n_neurons) { vA[i] = 0.0f; gacc[i] = 0.0f; }
    if (i < n_tm1) tm1_f[i] = 0.0f;
}

// --- build pass 1: per-(chunk,bucket) histogram; key = rowblk*NR + srcrange --
__global__ void bhist_kernel(const int* __restrict__ src,
                             const int* __restrict__ tgt,
                             int* __restrict__ blkhist,
                             int n_edges, int n_tm1, int nbkt, int NR, int nblk) {
    __shared__ int hist[BKMAX];
    int b = blockIdx.x;
    for (int i = threadIdx.x; i < nbkt; i += blockDim.x) hist[i] = 0;
    __syncthreads();
    int base = b * CHUNK;
    int end = min(base + CHUNK, n_edges);
    for (int k = base + threadIdx.x; k < end; k += blockDim.x) {
        int t = tgt[k];
        if (t >= n_tm1)
            atomicAdd(&hist[(t >> RBBITS) * NR + (src[k] >> SRBITS)], 1);
    }
    __syncthreads();
    for (int i = threadIdx.x; i < nbkt; i += blockDim.x)
        blkhist[(size_t)i * nblk + b] = hist[i];      // bucket-major for scan
}

// --- 3-level exclusive scan --------------------------------------------------
__global__ void scan1_kernel(const int* in, int* out, int* bsums, int n) {
    __shared__ int s[SCAN_B];
    int gid = blockIdx.x * SCAN_B + threadIdx.x;
    int x = (gid < n) ? in[gid] : 0;
    s[threadIdx.x] = x;
    __syncthreads();
    for (int off = 1; off < SCAN_B; off <<= 1) {
        int t = (threadIdx.x >= off) ? s[threadIdx.x - off] : 0;
        __syncthreads();
        s[threadIdx.x] += t;
        __syncthreads();
    }
    if (gid < n) out[gid] = s[threadIdx.x] - x;       // exclusive
    if (threadIdx.x == SCAN_B - 1) bsums[blockIdx.x] = s[SCAN_B - 1];
}

__global__ void scan2_kernel(int* bsums, int nb, int* total) {
    __shared__ int s[SCAN_B];
    int x = (threadIdx.x < nb) ? bsums[threadIdx.x] : 0;
    s[threadIdx.x] = x;
    __syncthreads();
    for (int off = 1; off < SCAN_B; off <<= 1) {
        int t = (threadIdx.x >= off) ? s[threadIdx.x - off] : 0;
        __syncthreads();
        s[threadIdx.x] += t;
        __syncthreads();
    }
    if (threadIdx.x == nb - 1) *total = s[threadIdx.x];   // inclusive grand total
    if (threadIdx.x < nb) bsums[threadIdx.x] = s[threadIdx.x] - x;
}

__global__ void scanadd_kernel(int* data, const int* __restrict__ bsums, int n) {
    int gid = blockIdx.x * blockDim.x + threadIdx.x;
    if (gid < n) data[gid] += bsums[gid / SCAN_B];
}

// --- build pass 2: bin kept edges into (rowblk,srcrange) buckets -------------
// record = (src_local | tgt_local<<SRBITS, weight-bits): 14+13 = 27 bits.
__global__ void bin_kernel(const int* __restrict__ src, const int* __restrict__ tgt,
                           const float* __restrict__ w, const int* __restrict__ scanned,
                           int2* __restrict__ edges, int n_edges, int n_tm1,
                           int nbkt, int NR, int nblk) {
    __shared__ int cur[BKMAX];
    int b = blockIdx.x;
    for (int i = threadIdx.x; i < nbkt; i += blockDim.x)
        cur[i] = scanned[(size_t)i * nblk + b];
    __syncthreads();
    int base = b * CHUNK;
    int end = min(base + CHUNK, n_edges);
    for (int k = base + threadIdx.x; k < end; k += blockDim.x) {
        int t = tgt[k];
        if (t < n_tm1) continue;                      // dead edges (dv[:tm1]=0)
        int s = src[k];
        int key = (t >> RBBITS) * NR + (s >> SRBITS);
        int pos = atomicAdd(&cur[key], 1);            // LDS atomic
        edges[pos] = make_int2((s & (SR - 1)) | ((t & (RB - 1)) << SRBITS),
                               __float_as_int(w[k]));
    }
}

// --- compact segment table: seg[i] = start of bucket i -----------------------
__global__ void mkseg_kernel(const int* __restrict__ scanned, int* __restrict__ seg,
                             const int* __restrict__ total, int nbkt, int nblk) {
    int i = blockIdx.x * blockDim.x + threadIdx.x;
    if (i < nbkt) seg[i] = scanned[(size_t)i * nblk];
    if (i == nbkt) seg[nbkt] = *total;
}

// --- per-step kernel 1: tiled gather, block = one (rowblk, srcrange) tile ----
// Stage relu(vr[srcrange]) -> tile (coalesced); edges: ds_read * w ->
// LDS atomicAdd acc; flush partial acc -> gacc (coalesced global atomics).
__global__ __launch_bounds__(1024)
void gather_kernel(const int* __restrict__ seg,
                   const int2* __restrict__ edges,
                   const float* __restrict__ vr,
                   float* __restrict__ gacc,
                   int n_neurons, int NR) {
    __shared__ float tile[SR];
    __shared__ float acc[RB];
    int tid = threadIdx.x;
    int bid = blockIdx.x;
    int rb = bid / NR;
    int r  = bid - rb * NR;
    int rowbase = rb << RBBITS;
    int sbase   = r << SRBITS;

    for (int i = tid; i < RB; i += 1024) acc[i] = 0.0f;
    if (sbase + SR <= n_neurons) {        // full range: float4 fast path
        const float4* v4 = (const float4*)(vr + sbase);
        float4* t4 = (float4*)tile;
        for (int i = tid; i < SR / 4; i += 1024) {
            float4 v = v4[i];
            v.x = fmaxf(v.x, 0.0f); v.y = fmaxf(v.y, 0.0f);
            v.z = fmaxf(v.z, 0.0f); v.w = fmaxf(v.w, 0.0f);
            t4[i] = v;
        }
    } else {                              // tail range: clamp
        for (int i = tid; i < SR; i += 1024) {
            int g = sbase + i;
            tile[i] = (g < n_neurons) ? fmaxf(vr[g], 0.0f) : 0.0f;
        }
    }
    __syncthreads();

    int e0 = seg[bid], e1 = seg[bid + 1];
    for (int e = e0 + tid; e < e1; e += 1024) {
        int2 rec = edges[e];
        atomicAdd(&acc[(unsigned)rec.x >> SRBITS],
                  tile[rec.x & (SR - 1)] * __int_as_float(rec.y));
    }
    __syncthreads();

    int lim = min(RB, n_neurons - rowbase);
    for (int i = tid; i < lim; i += 1024)
        atomicAdd(&gacc[rowbase + i], acc[i]);   // coalesced f32 atomics
}

// --- per-step kernel 2: consume gacc, integrate v, Tm1 filters, rezero gacc --
__global__ void update_kernel(const float* __restrict__ vr,
                              float* __restrict__ vw,
                              float* __restrict__ gacc,
                              float* __restrict__ tm1_f,
                              const float* __restrict__ x,   // tm1_input + k*n_tm1
                              const float* __restrict__ tau,
                              const float* __restrict__ vrest,
                              int n_neurons, int n_tm1, int last) {
    int i = blockIdx.x * blockDim.x + threadIdx.x;
    if (i >= n_neurons) return;
    if (i < n_tm1) {                      // Tm1 row: filter update only
        float cur = vr[i];                // = tm1_v at step k
        if (last) {
            vw[i] = cur;                  // ref: v[:tm1] = old tm1_v
        } else {
            float f  = tm1_f[i];
            float xk = x[i];
            float hp = xk - f;
            tm1_f[i] = f + DT * (xk - f) / TAU_HP;
            vw[i] = cur + DT * (fmaxf(hp, 0.0f) - cur) / TAU_LP;
        }
        gacc[i] = 0.0f;                   // keep clean for next step
    } else {
        float vi = vr[i];
        vw[i] = vi + DT * ((-vi + gacc[i] + vrest[i]) / tau[i]);
        gacc[i] = 0.0f;                   // rezero for next step's gather
    }
}

extern "C" void kernel_launch(void* const* d_in, const int* in_sizes, int n_in,
                              void* d_out, int out_size, void* d_ws, size_t ws_size,
                              hipStream_t stream) {
    const float* tm1_input  = (const float*)d_in[0];
    const float* weights    = (const float*)d_in[1];
    const float* tau        = (const float*)d_in[2];
    const float* vrest      = (const float*)d_in[3];
    const int*   source_idx = (const int*)d_in[4];
    const int*   target_idx = (const int*)d_in[5];

    const int n_edges   = in_sizes[1];
    const int n_neurons = in_sizes[2];
    const int n_tm1     = 25000;
    const int steps     = in_sizes[0] / n_tm1;

    const int NR     = (n_neurons + SR - 1) / SR;            // 13
    const int nbRows = (n_neurons + RB - 1) / RB;            // 25
    const int nbkt   = nbRows * NR;                          // 325 <= BKMAX
    const int nblk   = (n_edges + CHUNK - 1) / CHUNK;        // 196
    const int n_scan = nbkt * nblk;                          // 63,700

    // Workspace (4-byte units). edges first -> 16B aligned.
    size_t off = 0;
    auto alloc = [&](size_t n) { size_t o = off; off += n; return o; };
    int* ws_i = (int*)d_ws;
    float* ws_f = (float*)d_ws;

    int2*  edges   = (int2*)(ws_i + alloc((size_t)(n_edges + 2) * 2));
    float* vA      = ws_f + alloc(n_neurons);
    float* vB      = ws_f + alloc(n_neurons);
    float* tm1_f   = ws_f + alloc(n_tm1);
    float* gacc    = ws_f + alloc(n_neurons);
    int*   seg     = ws_i + alloc(nbkt + 1);
    int*   blkhist = ws_i + alloc((size_t)n_scan);
    int*   bsums   = ws_i + alloc(SCAN_B);
    int*   total   = ws_i + alloc(1);
    (void)ws_size;

    float* out = (float*)d_out;

    const int B = 256;
    const int gridN = (n_neurons + B - 1) / B;
    const int nScanBlocks = (n_scan + SCAN_B - 1) / SCAN_B;  // 63 <= 1024
    const int gridSA = (n_scan + B - 1) / B;
    const int gridSeg = (nbkt + 1 + B - 1) / B;
    const int gridU = (n_neurons + B - 1) / B;

    // --- one-time (per launch) CSR build: zero global atomics ---
    init_kernel<<<gridN, B, 0, stream>>>(vA, tm1_f, gacc, n_neurons, n_tm1);
    bhist_kernel<<<nblk, 1024, 0, stream>>>(source_idx, target_idx, blkhist,
                                            n_edges, n_tm1, nbkt, NR, nblk);
    scan1_kernel<<<nScanBlocks, SCAN_B, 0, stream>>>(blkhist, blkhist, bsums, n_scan);
    scan2_kernel<<<1, SCAN_B, 0, stream>>>(bsums, nScanBlocks, total);
    scanadd_kernel<<<gridSA, B, 0, stream>>>(blkhist, bsums, n_scan);
    bin_kernel<<<nblk, 1024, 0, stream>>>(source_idx, target_idx, weights, blkhist,
                                          edges, n_edges, n_tm1, nbkt, NR, nblk);
    mkseg_kernel<<<gridSeg, B, 0, stream>>>(blkhist, seg, total, nbkt, nblk);

    // --- steps: gather (tiled, LDS) + update, double-buffered v ---
    for (int k = 0; k < steps; ++k) {
        const float* vr = (k & 1) ? vB : vA;
        float* vw = (k == steps - 1) ? out : ((k & 1) ? vA : vB);
        gather_kernel<<<nbkt, 1024, 0, stream>>>(seg, edges, vr, gacc,
                                                 n_neurons, NR);
        update_kernel<<<gridU, B, 0, stream>>>(
            vr, vw, gacc, tm1_f,
            tm1_input + (size_t)k * n_tm1,
            tau, vrest, n_neurons, n_tm1, (k == steps - 1) ? 1 : 0);
    }
}

// Round 11
// 1754.788 us; speedup vs baseline: 2.1557x; 2.1557x over previous
//
#include <hip/hip_runtime.h>
#include <hip/hip_bf16.h>

#define DT 0.1f
#define TAU_HP 12.3f
#define TAU_LP 2.3f
#define SCAN_B 1024
#define CHUNK 32768        // edges per block in hist/bin passes (64K regressed: R10)

// R13 build: coarse bucket = 512 targets (tgt >> 9). 391 buckets.
#define BSHIFT 9
#define BMASK 511
#define NBKT_MAX 512
#define MWMAX 6400         // LDS mask words (supports n_neurons <= 204800)

// ---------------------------------------------------------------------------
// R5:  8 lanes/row remap. NEUTRAL -> not wave-slot-bound.
// R6:  cooperative all-steps kernel. 9457us. REVERTED.
// R7:  relu-mask w/ global reads. 2179us: mask load was itself VMEM.
// R8:  mask in LDS. 1779us BEST. Step = ~29us = 5.6M random line-reqs x ~3cy.
// R9:  direct-scatter build. 2123us (346MB writes). REVERTED.
// R10: CHUNK 64K. 1828us (bin occupancy halved). REVERTED.
// R11: tiled LDS gather RB=512. 3552us (tile shape: 1 edge/thread/barrier).
// R12: balanced tiles 16Kx8K. 3782us. Gather via LDS atomics ~2.3x worse
//      than random VMEM -> R8 step path is the empirical floor. CONFIRMED:
//      coarse buckets fix bin write amp (135->77us, 161->51MB).
// R13: R8 step path byte-identical. Build -> 2-level: coarse 512-target
//      buckets for bhist/scan/bin (fewer, longer write runs; 4x smaller
//      scans), then finalize2 (391 blocks, 2-pass: LDS hist(512)+scan ->
//      row_start; re-read + LDS-cursor scatter -> final per-target CSR).
//      Replaces {bin 135 + finalize ~50} with {bin ~90 + finalize2 ~30}.
// ---------------------------------------------------------------------------

__global__ void init_kernel(float* __restrict__ vA,
                            float* __restrict__ tm1_f,
                            unsigned* __restrict__ mask3,
                            int n_neurons, int n_tm1, int mask3_words) {
    int i = blockIdx.x * blockDim.x + threadIdx.x;
    if (i < n_neurons) vA[i] = 0.0f;
    if (i < n_tm1) tm1_f[i] = 0.0f;
    if (i < mask3_words) mask3[i] = 0u;
}

// --- build pass 1: per-(chunk,bucket) histogram (Tm1 targets dropped) --------
__global__ void bhist_kernel(const int* __restrict__ tgt, int* __restrict__ blkhist,
                             int n_edges, int n_tm1, int nb, int nblk) {
    __shared__ int hist[NBKT_MAX];
    int b = blockIdx.x;
    for (int i = threadIdx.x; i < nb; i += blockDim.x) hist[i] = 0;
    __syncthreads();
    int base = b * CHUNK;
    int end = min(base + CHUNK, n_edges);
    for (int k = base + threadIdx.x; k < end; k += blockDim.x) {
        int t = tgt[k];
        if (t >= n_tm1) atomicAdd(&hist[t >> BSHIFT], 1);
    }
    __syncthreads();
    for (int i = threadIdx.x; i < nb; i += blockDim.x)
        blkhist[(size_t)i * nblk + b] = hist[i];      // bucket-major for scan
}

// --- 3-level exclusive scan --------------------------------------------------
__global__ void scan1_kernel(const int* in, int* out, int* bsums, int n) {
    __shared__ int s[SCAN_B];
    int gid = blockIdx.x * SCAN_B + threadIdx.x;
    int x = (gid < n) ? in[gid] : 0;
    s[threadIdx.x] = x;
    __syncthreads();
    for (int off = 1; off < SCAN_B; off <<= 1) {
        int t = (threadIdx.x >= off) ? s[threadIdx.x - off] : 0;
        __syncthreads();
        s[threadIdx.x] += t;
        __syncthreads();
    }
    if (gid < n) out[gid] = s[threadIdx.x] - x;       // exclusive
    if (threadIdx.x == SCAN_B - 1) bsums[blockIdx.x] = s[SCAN_B - 1];
}

__global__ void scan2_kernel(int* bsums, int nb, int* total) {
    __shared__ int s[SCAN_B];
    int x = (threadIdx.x < nb) ? bsums[threadIdx.x] : 0;
    s[threadIdx.x] = x;
    __syncthreads();
    for (int off = 1; off < SCAN_B; off <<= 1) {
        int t = (threadIdx.x >= off) ? s[threadIdx.x - off] : 0;
        __syncthreads();
        s[threadIdx.x] += t;
        __syncthreads();
    }
    if (threadIdx.x == nb - 1) *total = s[threadIdx.x];   // inclusive grand total
    if (threadIdx.x < nb) bsums[threadIdx.x] = s[threadIdx.x] - x;
}

__global__ void scanadd_kernel(int* data, const int* __restrict__ bsums, int n) {
    int gid = blockIdx.x * blockDim.x + threadIdx.x;
    if (gid < n) data[gid] += bsums[gid / SCAN_B];
}

// --- build pass 2: bin kept edges into coarse-bucket order (LDS cursors) -----
// record = (src | tlow<<18, weight-bits); src < 2^18, tlow 9 bits.
__global__ void bin_kernel(const int* __restrict__ src, const int* __restrict__ tgt,
                           const float* __restrict__ w, const int* __restrict__ scanned,
                           int2* __restrict__ ebuf, int n_edges, int n_tm1,
                           int nb, int nblk) {
    __shared__ int cur[NBKT_MAX];
    int b = blockIdx.x;
    for (int i = threadIdx.x; i < nb; i += blockDim.x)
        cur[i] = scanned[(size_t)i * nblk + b];
    __syncthreads();
    int base = b * CHUNK;
    int end = min(base + CHUNK, n_edges);
    for (int k = base + threadIdx.x; k < end; k += blockDim.x) {
        int t = tgt[k];
        if (t < n_tm1) continue;                      // dead edges (dv[:tm1]=0)
        int pos = atomicAdd(&cur[t >> BSHIFT], 1);    // LDS atomic
        ebuf[pos] = make_int2(src[k] | ((t & BMASK) << 18), __float_as_int(w[k]));
    }
}

// --- build pass 3: per-bucket 2-pass counting sort -> final CSR + row_start --
__global__ __launch_bounds__(1024)
void finalize2_kernel(const int2* __restrict__ ebuf, int2* __restrict__ edges,
                      const int* __restrict__ scanned, int* __restrict__ row_start,
                      const int* __restrict__ total, int n_neurons,
                      int nb, int nblk) {
    __shared__ int hist[BMASK + 1], ls[BMASK + 1], cur[BMASK + 1];
    int tid = threadIdx.x;
    int b = blockIdx.x;
    int beg = scanned[(size_t)b * nblk];
    int end = (b == nb - 1) ? *total : scanned[(size_t)(b + 1) * nblk];

    if (tid <= BMASK) hist[tid] = 0;
    __syncthreads();
    for (int k = beg + tid; k < end; k += 1024)
        atomicAdd(&hist[(ebuf[k].x >> 18) & BMASK], 1);
    __syncthreads();
    if (tid <= BMASK) ls[tid] = hist[tid];
    __syncthreads();
    for (int off = 1; off <= BMASK; off <<= 1) {
        int t = (tid <= BMASK && tid >= off) ? ls[tid - off] : 0;
        __syncthreads();
        if (tid <= BMASK) ls[tid] += t;               // inclusive
        __syncthreads();
    }
    if (tid <= BMASK) {
        int excl = ls[tid] - hist[tid];
        cur[tid] = excl;
        int t = (b << BSHIFT) + tid;
        if (t < n_neurons) row_start[t] = beg + excl;
    }
    if (b == nb - 1 && tid == 0) row_start[n_neurons] = *total;
    __syncthreads();
    for (int k = beg + tid; k < end; k += 1024) {
        int2 r = ebuf[k];
        int pos = atomicAdd(&cur[(r.x >> 18) & BMASK], 1);  // LDS atomic
        edges[beg + pos] = make_int2(r.x & 0x3FFFF, r.y);
    }
}

// --- fused per-step kernel (LDS relu-bitmask skip) — byte-identical to R8 ----
__global__ __launch_bounds__(1024)
void step_kernel(const int* __restrict__ row_start,
                 const int2* __restrict__ edges,
                 const float* __restrict__ vr,
                 float* __restrict__ vw,
                 float* __restrict__ tm1_f,
                 const float* __restrict__ x,     // tm1_input + k*n_tm1
                 const float* __restrict__ tau,
                 const float* __restrict__ vrest,
                 const unsigned* __restrict__ maskR,
                 unsigned* __restrict__ maskW,
                 unsigned* __restrict__ maskC,
                 int mask_words,
                 int n_neurons, int n_tm1, int gbase, int last) {
    __shared__ unsigned smask[MWMAX];
    int g = blockIdx.x * blockDim.x + threadIdx.x;

    // uniform per-block: does this block contain gather threads?
    if ((int)((blockIdx.x + 1) * blockDim.x) > gbase) {
        for (int i = threadIdx.x; i < mask_words; i += blockDim.x)
            smask[i] = maskR[i];
        __syncthreads();
    }

    if (g < gbase) {                         // Tm1 region (wave-uniform branch)
        if (g < mask_words) maskC[g] = 0u;   // clear the idle buffer for step k+1
        float val = 0.0f;
        bool wrote = false;
        if (g < n_tm1) {
            float cur = vr[g];               // = tm1_v at step k
            if (last) {
                val = cur;                   // ref: v[:tm1] = old tm1_v
            } else {
                float f  = tm1_f[g];
                float xk = x[g];
                float hp = xk - f;
                tm1_f[g] = f + DT * (xk - f) / TAU_HP;
                val = cur + DT * (fmaxf(hp, 0.0f) - cur) / TAU_LP;
            }
            vw[g] = val;
            wrote = true;
        }
        // ballot mask write: 64 consecutive ids per wave, 2 words
        unsigned long long bm = __ballot(wrote && (val > 0.0f));
        int l = threadIdx.x & 63;
        unsigned lo = (unsigned)(bm & 0xffffffffull);
        unsigned hi = (unsigned)(bm >> 32);
        if (l == 0 && lo)  atomicOr(&maskW[g >> 5], lo);
        if (l == 32 && hi) atomicOr(&maskW[g >> 5], hi);
        return;
    }

    int t = g - gbase;
    int row = n_tm1 + (t >> 3);
    int lane = t & 7;
    bool active = (row < n_neurons);
    float sum = 0.0f;
    float vnew = 0.0f;

    if (active) {
        int s = row_start[row];
        int e = row_start[row + 1];
        for (int p = (s & ~1) + 2 * lane; p < e; p += 16) {
            int4 q = *(const int4*)(edges + p);  // 16B aligned (p even)
            // bit==1 implies vr>0 -> relu redundant; bit==0 -> term exactly 0
            bool a0 = (p >= s)    && ((smask[(unsigned)q.x >> 5] >> (q.x & 31)) & 1u);
            bool a1 = (p + 1 < e) && ((smask[(unsigned)q.z >> 5] >> (q.z & 31)) & 1u);
            if (a0) sum += vr[q.x] * __int_as_float(q.y);
            if (a1) sum += vr[q.z] * __int_as_float(q.w);
        }
    }
    sum += __shfl_xor(sum, 4);
    sum += __shfl_xor(sum, 2);
    sum += __shfl_xor(sum, 1);
    if (active && lane == 0) {
        float vi = vr[row];
        vnew = vi + DT * ((-vi + sum + vrest[row]) / tau[row]);
        vw[row] = vnew;
    }
    // wave-level mask write: 8 rows/wave at bit offset (row0&31) in {0,8,16,24}
    unsigned long long bm = __ballot(active && lane == 0 && vnew > 0.0f);
    if ((threadIdx.x & 63) == 0) {
        unsigned b8 = 0;
        #pragma unroll
        for (int i = 0; i < 8; ++i) b8 |= (unsigned)((bm >> (8 * i)) & 1ull) << i;
        if (b8) {
            int row0 = n_tm1 + (t >> 3);     // this lane's row = wave's first row
            atomicOr(&maskW[row0 >> 5], b8 << (row0 & 31));
        }
    }
}

extern "C" void kernel_launch(void* const* d_in, const int* in_sizes, int n_in,
                              void* d_out, int out_size, void* d_ws, size_t ws_size,
                              hipStream_t stream) {
    const float* tm1_input  = (const float*)d_in[0];
    const float* weights    = (const float*)d_in[1];
    const float* tau        = (const float*)d_in[2];
    const float* vrest      = (const float*)d_in[3];
    const int*   source_idx = (const int*)d_in[4];
    const int*   target_idx = (const int*)d_in[5];

    const int n_edges   = in_sizes[1];
    const int n_neurons = in_sizes[2];
    const int n_tm1     = 25000;
    const int steps     = in_sizes[0] / n_tm1;

    const int nb   = (n_neurons + BMASK) >> BSHIFT;          // 391 buckets
    const int nblk = (n_edges + CHUNK - 1) / CHUNK;          // 196
    const int n_scan = nb * nblk;                            // 76,636
    const int mask_words = (n_neurons + 31) >> 5;            // 6250 <= MWMAX

    // Workspace (4-byte units). edges/ebuf first -> 16B aligned for int4.
    size_t off = 0;
    auto alloc = [&](size_t n) { size_t o = off; off += n; return o; };
    int* ws_i = (int*)d_ws;
    float* ws_f = (float*)d_ws;

    int2*     edges     = (int2*)(ws_i + alloc((size_t)(n_edges + 2) * 2));
    int2*     ebuf      = (int2*)(ws_i + alloc((size_t)(n_edges + 2) * 2));
    float*    vA        = ws_f + alloc(n_neurons);
    float*    vB        = ws_f + alloc(n_neurons);
    float*    tm1_f     = ws_f + alloc(n_tm1);
    int*      row_start = ws_i + alloc(n_neurons + 1);
    unsigned* mask3     = (unsigned*)(ws_i + alloc((size_t)3 * mask_words));
    int*      blkhist   = ws_i + alloc((size_t)n_scan);
    int*      bsums     = ws_i + alloc(SCAN_B);
    int*      total     = ws_i + alloc(1);
    (void)ws_size;

    float* out = (float*)d_out;

    const int B = 256;
    const int gridN = (n_neurons + B - 1) / B;
    const int nScanBlocks = (n_scan + SCAN_B - 1) / SCAN_B;  // 75 <= 1024
    const int gridSA = (n_scan + B - 1) / B;

    // Step-kernel thread map: Tm1 rows 1:1, then wave-aligned 8-lane groups.
    const int SB = 1024;
    const int gbase = (n_tm1 + 63) & ~63;
    const int work  = gbase + (n_neurons - n_tm1) * 8;
    const int gridG = (work + SB - 1) / SB;

    // --- one-time (per launch) CSR build: coarse radix + 2-pass finalize ---
    init_kernel<<<gridN, B, 0, stream>>>(vA, tm1_f, mask3, n_neurons, n_tm1,
                                         3 * mask_words);
    bhist_kernel<<<nblk, 1024, 0, stream>>>(target_idx, blkhist, n_edges, n_tm1,
                                            nb, nblk);
    scan1_kernel<<<nScanBlocks, SCAN_B, 0, stream>>>(blkhist, blkhist, bsums, n_scan);
    scan2_kernel<<<1, SCAN_B, 0, stream>>>(bsums, nScanBlocks, total);
    scanadd_kernel<<<gridSA, B, 0, stream>>>(blkhist, bsums, n_scan);
    bin_kernel<<<nblk, 1024, 0, stream>>>(source_idx, target_idx, weights, blkhist,
                                          ebuf, n_edges, n_tm1, nb, nblk);
    finalize2_kernel<<<nb, 1024, 0, stream>>>(ebuf, edges, blkhist, row_start,
                                              total, n_neurons, nb, nblk);

    // --- steps: ONE fused kernel per step, double-buffered v, rotating mask ---
    for (int k = 0; k < steps; ++k) {
        const float* vr = (k & 1) ? vB : vA;
        float* vw = (k == steps - 1) ? out : ((k & 1) ? vA : vB);
        unsigned* mW = mask3 + (size_t)(k % 3) * mask_words;
        unsigned* mR = mask3 + (size_t)((k + 2) % 3) * mask_words;
        unsigned* mC = mask3 + (size_t)((k + 1) % 3) * mask_words;
        step_kernel<<<gridG, SB, 0, stream>>>(
            row_start, edges, vr, vw, tm1_f,
            tm1_input + (size_t)k * n_tm1,
            tau, vrest, mR, mW, mC, mask_words,
            n_neurons, n_tm1, gbase, (k == steps - 1) ? 1 : 0);
    }
}

// Round 13
// 1747.697 us; speedup vs baseline: 2.1645x; 1.0041x over previous
//
#include <hip/hip_runtime.h>
#include <hip/hip_bf16.h>

#define DT 0.1f
#define TAU_HP 12.3f
#define TAU_LP 2.3f
#define SCAN_B 1024
#define CHUNK 16384        // R14: 392 blocks (196 left 60 CUs idle; 98 hurt: R10)

// Coarse bucket = 512 targets (tgt >> 9). 391 buckets.
#define BSHIFT 9
#define BMASK 511
#define NBKT_MAX 512
#define NSUB 8             // bhist sub-histograms (contention /8)
#define F2_CAP 16896       // finalize2 LDS records: mean 14.3K + 21 sigma
#define MWMAX 6400         // LDS mask words (supports n_neurons <= 204800)

// ---------------------------------------------------------------------------
// R5:  8 lanes/row remap. NEUTRAL -> not wave-slot-bound.
// R6:  cooperative all-steps. 9457us. REVERTED.
// R7:  relu-mask w/ global reads. 2179us. REVERTED (mask load was VMEM).
// R8:  mask in LDS. 1779us. Step = ~28us = 5.6M random L2-line-reqs x ~3cy
//      (invariant across 5 step configs -> step at HW floor).
// R9:  direct-scatter build. 2123us (346MB writes). REVERTED.
// R10: CHUNK 64K. 1828us (98 blocks -> CUs idle). REVERTED.
// R11/R12: LDS-tiled gather. 3552/3782us. REVERTED (LDS atomics 2.3x worse).
// R13: coarse 512-target buckets + 2-pass finalize2. 1754.8us BEST.
//      bin 135->85us, WRITE 147->57MB (write-locality theory confirmed 2x).
// R14: build-only package (step byte-identical):
//      (a) CHUNK 16K -> 392 blocks: all 256 CUs busy in bhist/bin.
//      (b) bhist 8-way sub-histograms: LDS atomic contention /8.
//      (c) finalize2 single-pass: bucket staged in LDS (132KB) -> ebuf read
//          once, not twice.
//      (resubmitted unmeasured: round 12 hit GPUAcquisitionTimeout)
// ---------------------------------------------------------------------------

__global__ void init_kernel(float* __restrict__ vA,
                            float* __restrict__ tm1_f,
                            unsigned* __restrict__ mask3,
                            int n_neurons, int n_tm1, int mask3_words) {
    int i = blockIdx.x * blockDim.x + threadIdx.x;
    if (i < n_neurons) vA[i] = 0.0f;
    if (i < n_tm1) tm1_f[i] = 0.0f;
    if (i < mask3_words) mask3[i] = 0u;
}

// --- build pass 1: per-(chunk,bucket) histogram, 8-way split -----------------
__global__ void bhist_kernel(const int* __restrict__ tgt, int* __restrict__ blkhist,
                             int n_edges, int n_tm1, int nb, int nblk) {
    __shared__ int hist[NSUB][NBKT_MAX];
    int b = blockIdx.x;
    for (int i = threadIdx.x; i < NSUB * NBKT_MAX; i += blockDim.x)
        ((int*)hist)[i] = 0;
    __syncthreads();
    int sub = threadIdx.x >> 7;              // 128 threads (2 waves) per copy
    int base = b * CHUNK;
    int end = min(base + CHUNK, n_edges);
    for (int k = base + threadIdx.x; k < end; k += blockDim.x) {
        int t = tgt[k];
        if (t >= n_tm1) atomicAdd(&hist[sub][t >> BSHIFT], 1);
    }
    __syncthreads();
    for (int i = threadIdx.x; i < nb; i += blockDim.x) {
        int s = 0;
        #pragma unroll
        for (int j = 0; j < NSUB; ++j) s += hist[j][i];
        blkhist[(size_t)i * nblk + b] = s;   // bucket-major for scan
    }
}

// --- 3-level exclusive scan --------------------------------------------------
__global__ void scan1_kernel(const int* in, int* out, int* bsums, int n) {
    __shared__ int s[SCAN_B];
    int gid = blockIdx.x * SCAN_B + threadIdx.x;
    int x = (gid < n) ? in[gid] : 0;
    s[threadIdx.x] = x;
    __syncthreads();
    for (int off = 1; off < SCAN_B; off <<= 1) {
        int t = (threadIdx.x >= off) ? s[threadIdx.x - off] : 0;
        __syncthreads();
        s[threadIdx.x] += t;
        __syncthreads();
    }
    if (gid < n) out[gid] = s[threadIdx.x] - x;       // exclusive
    if (threadIdx.x == SCAN_B - 1) bsums[blockIdx.x] = s[SCAN_B - 1];
}

__global__ void scan2_kernel(int* bsums, int nb, int* total) {
    __shared__ int s[SCAN_B];
    int x = (threadIdx.x < nb) ? bsums[threadIdx.x] : 0;
    s[threadIdx.x] = x;
    __syncthreads();
    for (int off = 1; off < SCAN_B; off <<= 1) {
        int t = (threadIdx.x >= off) ? s[threadIdx.x - off] : 0;
        __syncthreads();
        s[threadIdx.x] += t;
        __syncthreads();
    }
    if (threadIdx.x == nb - 1) *total = s[threadIdx.x];   // inclusive grand total
    if (threadIdx.x < nb) bsums[threadIdx.x] = s[threadIdx.x] - x;
}

__global__ void scanadd_kernel(int* data, const int* __restrict__ bsums, int n) {
    int gid = blockIdx.x * blockDim.x + threadIdx.x;
    if (gid < n) data[gid] += bsums[gid / SCAN_B];
}

// --- build pass 2: bin kept edges into coarse-bucket order (LDS cursors) -----
// record = (src | tlow<<18, weight-bits); src < 2^18, tlow 9 bits.
__global__ void bin_kernel(const int* __restrict__ src, const int* __restrict__ tgt,
                           const float* __restrict__ w, const int* __restrict__ scanned,
                           int2* __restrict__ ebuf, int n_edges, int n_tm1,
                           int nb, int nblk) {
    __shared__ int cur[NBKT_MAX];
    int b = blockIdx.x;
    for (int i = threadIdx.x; i < nb; i += blockDim.x)
        cur[i] = scanned[(size_t)i * nblk + b];
    __syncthreads();
    int base = b * CHUNK;
    int end = min(base + CHUNK, n_edges);
    for (int k = base + threadIdx.x; k < end; k += blockDim.x) {
        int t = tgt[k];
        if (t < n_tm1) continue;                      // dead edges (dv[:tm1]=0)
        int pos = atomicAdd(&cur[t >> BSHIFT], 1);    // LDS atomic
        ebuf[pos] = make_int2(src[k] | ((t & BMASK) << 18), __float_as_int(w[k]));
    }
}

// --- build pass 3: per-bucket single-pass counting sort (bucket in LDS) ------
__global__ __launch_bounds__(1024)
void finalize2_kernel(const int2* __restrict__ ebuf, int2* __restrict__ edges,
                      const int* __restrict__ scanned, int* __restrict__ row_start,
                      const int* __restrict__ total, int n_neurons,
                      int nb, int nblk) {
    __shared__ int2 buf[F2_CAP];
    __shared__ int hist[BMASK + 1], ls[BMASK + 1], cur[BMASK + 1];
    int tid = threadIdx.x;
    int b = blockIdx.x;
    int beg = scanned[(size_t)b * nblk];
    int end = (b == nb - 1) ? *total : scanned[(size_t)(b + 1) * nblk];
    int n = min(end - beg, F2_CAP);

    for (int k = tid; k < n; k += 1024) buf[k] = ebuf[beg + k];
    if (tid <= BMASK) hist[tid] = 0;
    __syncthreads();
    for (int k = tid; k < n; k += 1024)
        atomicAdd(&hist[(buf[k].x >> 18) & BMASK], 1);
    __syncthreads();
    if (tid <= BMASK) ls[tid] = hist[tid];
    __syncthreads();
    for (int off = 1; off <= BMASK; off <<= 1) {
        int t = (tid <= BMASK && tid >= off) ? ls[tid - off] : 0;
        __syncthreads();
        if (tid <= BMASK) ls[tid] += t;               // inclusive
        __syncthreads();
    }
    if (tid <= BMASK) {
        int excl = ls[tid] - hist[tid];
        cur[tid] = excl;
        int t = (b << BSHIFT) + tid;
        if (t < n_neurons) row_start[t] = beg + excl;
    }
    if (b == nb - 1 && tid == 0) row_start[n_neurons] = *total;
    __syncthreads();
    for (int k = tid; k < n; k += 1024) {
        int2 r = buf[k];
        int pos = atomicAdd(&cur[(r.x >> 18) & BMASK], 1);  // LDS atomic
        edges[beg + pos] = make_int2(r.x & 0x3FFFF, r.y);
    }
}

// --- fused per-step kernel (LDS relu-bitmask skip) — byte-identical to R8 ----
__global__ __launch_bounds__(1024)
void step_kernel(const int* __restrict__ row_start,
                 const int2* __restrict__ edges,
                 const float* __restrict__ vr,
                 float* __restrict__ vw,
                 float* __restrict__ tm1_f,
                 const float* __restrict__ x,     // tm1_input + k*n_tm1
                 const float* __restrict__ tau,
                 const float* __restrict__ vrest,
                 const unsigned* __restrict__ maskR,
                 unsigned* __restrict__ maskW,
                 unsigned* __restrict__ maskC,
                 int mask_words,
                 int n_neurons, int n_tm1, int gbase, int last) {
    __shared__ unsigned smask[MWMAX];
    int g = blockIdx.x * blockDim.x + threadIdx.x;

    // uniform per-block: does this block contain gather threads?
    if ((int)((blockIdx.x + 1) * blockDim.x) > gbase) {
        for (int i = threadIdx.x; i < mask_words; i += blockDim.x)
            smask[i] = maskR[i];
        __syncthreads();
    }

    if (g < gbase) {                         // Tm1 region (wave-uniform branch)
        if (g < mask_words) maskC[g] = 0u;   // clear the idle buffer for step k+1
        float val = 0.0f;
        bool wrote = false;
        if (g < n_tm1) {
            float cur = vr[g];               // = tm1_v at step k
            if (last) {
                val = cur;                   // ref: v[:tm1] = old tm1_v
            } else {
                float f  = tm1_f[g];
                float xk = x[g];
                float hp = xk - f;
                tm1_f[g] = f + DT * (xk - f) / TAU_HP;
                val = cur + DT * (fmaxf(hp, 0.0f) - cur) / TAU_LP;
            }
            vw[g] = val;
            wrote = true;
        }
        // ballot mask write: 64 consecutive ids per wave, 2 words
        unsigned long long bm = __ballot(wrote && (val > 0.0f));
        int l = threadIdx.x & 63;
        unsigned lo = (unsigned)(bm & 0xffffffffull);
        unsigned hi = (unsigned)(bm >> 32);
        if (l == 0 && lo)  atomicOr(&maskW[g >> 5], lo);
        if (l == 32 && hi) atomicOr(&maskW[g >> 5], hi);
        return;
    }

    int t = g - gbase;
    int row = n_tm1 + (t >> 3);
    int lane = t & 7;
    bool active = (row < n_neurons);
    float sum = 0.0f;
    float vnew = 0.0f;

    if (active) {
        int s = row_start[row];
        int e = row_start[row + 1];
        for (int p = (s & ~1) + 2 * lane; p < e; p += 16) {
            int4 q = *(const int4*)(edges + p);  // 16B aligned (p even)
            // bit==1 implies vr>0 -> relu redundant; bit==0 -> term exactly 0
            bool a0 = (p >= s)    && ((smask[(unsigned)q.x >> 5] >> (q.x & 31)) & 1u);
            bool a1 = (p + 1 < e) && ((smask[(unsigned)q.z >> 5] >> (q.z & 31)) & 1u);
            if (a0) sum += vr[q.x] * __int_as_float(q.y);
            if (a1) sum += vr[q.z] * __int_as_float(q.w);
        }
    }
    sum += __shfl_xor(sum, 4);
    sum += __shfl_xor(sum, 2);
    sum += __shfl_xor(sum, 1);
    if (active && lane == 0) {
        float vi = vr[row];
        vnew = vi + DT * ((-vi + sum + vrest[row]) / tau[row]);
        vw[row] = vnew;
    }
    // wave-level mask write: 8 rows/wave at bit offset (row0&31) in {0,8,16,24}
    unsigned long long bm = __ballot(active && lane == 0 && vnew > 0.0f);
    if ((threadIdx.x & 63) == 0) {
        unsigned b8 = 0;
        #pragma unroll
        for (int i = 0; i < 8; ++i) b8 |= (unsigned)((bm >> (8 * i)) & 1ull) << i;
        if (b8) {
            int row0 = n_tm1 + (t >> 3);     // this lane's row = wave's first row
            atomicOr(&maskW[row0 >> 5], b8 << (row0 & 31));
        }
    }
}

extern "C" void kernel_launch(void* const* d_in, const int* in_sizes, int n_in,
                              void* d_out, int out_size, void* d_ws, size_t ws_size,
                              hipStream_t stream) {
    const float* tm1_input  = (const float*)d_in[0];
    const float* weights    = (const float*)d_in[1];
    const float* tau        = (const float*)d_in[2];
    const float* vrest      = (const float*)d_in[3];
    const int*   source_idx = (const int*)d_in[4];
    const int*   target_idx = (const int*)d_in[5];

    const int n_edges   = in_sizes[1];
    const int n_neurons = in_sizes[2];
    const int n_tm1     = 25000;
    const int steps     = in_sizes[0] / n_tm1;

    const int nb   = (n_neurons + BMASK) >> BSHIFT;          // 391 buckets
    const int nblk = (n_edges + CHUNK - 1) / CHUNK;          // 392
    const int n_scan = nb * nblk;                            // 153,272
    const int mask_words = (n_neurons + 31) >> 5;            // 6250 <= MWMAX

    // Workspace (4-byte units). edges/ebuf first -> 16B aligned for int4.
    size_t off = 0;
    auto alloc = [&](size_t n) { size_t o = off; off += n; return o; };
    int* ws_i = (int*)d_ws;
    float* ws_f = (float*)d_ws;

    int2*     edges     = (int2*)(ws_i + alloc((size_t)(n_edges + 2) * 2));
    int2*     ebuf      = (int2*)(ws_i + alloc((size_t)(n_edges + 2) * 2));
    float*    vA        = ws_f + alloc(n_neurons);
    float*    vB        = ws_f + alloc(n_neurons);
    float*    tm1_f     = ws_f + alloc(n_tm1);
    int*      row_start = ws_i + alloc(n_neurons + 1);
    unsigned* mask3     = (unsigned*)(ws_i + alloc((size_t)3 * mask_words));
    int*      blkhist   = ws_i + alloc((size_t)n_scan);
    int*      bsums     = ws_i + alloc(SCAN_B);
    int*      total     = ws_i + alloc(1);
    (void)ws_size;

    float* out = (float*)d_out;

    const int B = 256;
    const int gridN = (n_neurons + B - 1) / B;
    const int nScanBlocks = (n_scan + SCAN_B - 1) / SCAN_B;  // 150 <= 1024
    const int gridSA = (n_scan + B - 1) / B;

    // Step-kernel thread map: Tm1 rows 1:1, then wave-aligned 8-lane groups.
    const int SB = 1024;
    const int gbase = (n_tm1 + 63) & ~63;
    const int work  = gbase + (n_neurons - n_tm1) * 8;
    const int gridG = (work + SB - 1) / SB;

    // --- one-time (per launch) CSR build: coarse radix + 1-pass finalize ---
    init_kernel<<<gridN, B, 0, stream>>>(vA, tm1_f, mask3, n_neurons, n_tm1,
                                         3 * mask_words);
    bhist_kernel<<<nblk, 1024, 0, stream>>>(target_idx, blkhist, n_edges, n_tm1,
                                            nb, nblk);
    scan1_kernel<<<nScanBlocks, SCAN_B, 0, stream>>>(blkhist, blkhist, bsums, n_scan);
    scan2_kernel<<<1, SCAN_B, 0, stream>>>(bsums, nScanBlocks, total);
    scanadd_kernel<<<gridSA, B, 0, stream>>>(blkhist, bsums, n_scan);
    bin_kernel<<<nblk, 1024, 0, stream>>>(source_idx, target_idx, weights, blkhist,
                                          ebuf, n_edges, n_tm1, nb, nblk);
    finalize2_kernel<<<nb, 1024, 0, stream>>>(ebuf, edges, blkhist, row_start,
                                              total, n_neurons, nb, nblk);

    // --- steps: ONE fused kernel per step, double-buffered v, rotating mask ---
    for (int k = 0; k < steps; ++k) {
        const float* vr = (k & 1) ? vB : vA;
        float* vw = (k == steps - 1) ? out : ((k & 1) ? vA : vB);
        unsigned* mW = mask3 + (size_t)(k % 3) * mask_words;
        unsigned* mR = mask3 + (size_t)((k + 2) % 3) * mask_words;
        unsigned* mC = mask3 + (size_t)((k + 1) % 3) * mask_words;
        step_kernel<<<gridG, SB, 0, stream>>>(
            row_start, edges, vr, vw, tm1_f,
            tm1_input + (size_t)k * n_tm1,
            tau, vrest, mR, mW, mC, mask_words,
            n_neurons, n_tm1, gbase, (k == steps - 1) ? 1 : 0);
    }
}